// Round 2
// baseline (3897.784 us; speedup 1.0000x reference)
//
#include <hip/hip_runtime.h>

#define N_USERS 100000
#define M_ITEMS 50000
#define N_NODES 150000
#define N_EDGES 6000000
#define DIM 64

// ---------------- init: h_cur = acc = concat(user_emb, item_emb) ----------------
__global__ void init_kernel(const float4* __restrict__ user_emb,
                            const float4* __restrict__ item_emb,
                            float4* __restrict__ h_cur,
                            float4* __restrict__ acc) {
    const int n_user4 = N_USERS * DIM / 4;   // 1,600,000
    const int n_tot4  = N_NODES * DIM / 4;   // 2,400,000
    int i = blockIdx.x * blockDim.x + threadIdx.x;
    if (i < n_tot4) {
        float4 v = (i < n_user4) ? user_emb[i] : item_emb[i - n_user4];
        h_cur[i] = v;
        acc[i]   = v;
    }
}

// ---------------- zero a float4 buffer (graph-capture-safe memset) --------------
__global__ void zero_kernel(float4* __restrict__ p, int n4) {
    int i = blockIdx.x * blockDim.x + threadIdx.x;
    if (i < n4) {
        p[i] = make_float4(0.f, 0.f, 0.f, 0.f);
    }
}

// ---------------- spmm scatter: one wave per edge, lane = dim -------------------
__global__ void spmm_scatter(const int*   __restrict__ src,
                             const int*   __restrict__ dst,
                             const float* __restrict__ val,
                             const float* __restrict__ h_in,
                             float*       __restrict__ h_out) {
    int lane = threadIdx.x & 63;
    int wid  = (blockIdx.x * blockDim.x + threadIdx.x) >> 6;
    int nw   = (gridDim.x * blockDim.x) >> 6;
    for (int e = wid; e < N_EDGES; e += nw) {
        int   s = src[e];
        int   d = dst[e];
        float v = val[e];
        float m = h_in[s * DIM + lane] * v;
        atomicAdd(&h_out[d * DIM + lane], m);
    }
}

// ---------------- acc += h ------------------------------------------------------
__global__ void add_kernel(float4* __restrict__ acc,
                           const float4* __restrict__ h, int n4) {
    int i = blockIdx.x * blockDim.x + threadIdx.x;
    if (i < n4) {
        float4 a = acc[i];
        float4 b = h[i];
        a.x += b.x; a.y += b.y; a.z += b.z; a.w += b.w;
        acc[i] = a;
    }
}

// ---------------- acc = (acc + h) * s  (final layer, fused scale) ---------------
__global__ void add_scale_kernel(float4* __restrict__ acc,
                                 const float4* __restrict__ h, int n4, float s) {
    int i = blockIdx.x * blockDim.x + threadIdx.x;
    if (i < n4) {
        float4 a = acc[i];
        float4 b = h[i];
        a.x = (a.x + b.x) * s;
        a.y = (a.y + b.y) * s;
        a.z = (a.z + b.z) * s;
        a.w = (a.w + b.w) * s;
        acc[i] = a;
    }
}

extern "C" void kernel_launch(void* const* d_in, const int* in_sizes, int n_in,
                              void* d_out, int out_size, void* d_ws, size_t ws_size,
                              hipStream_t stream) {
    const float* user_emb = (const float*)d_in[0];
    const float* item_emb = (const float*)d_in[1];
    const int*   edge_src = (const int*)d_in[2];
    const int*   edge_dst = (const int*)d_in[3];
    const float* edge_val = (const float*)d_in[4];
    float* out = (float*)d_out;

    float* h_a = (float*)d_ws;                     // 9.6M floats
    float* h_b = h_a + (size_t)N_NODES * DIM;      // 9.6M floats

    const int n4 = N_NODES * DIM / 4;              // 2,400,000
    const int ew_blocks = (n4 + 255) / 256;        // elementwise grid

    init_kernel<<<ew_blocks, 256, 0, stream>>>((const float4*)user_emb,
                                               (const float4*)item_emb,
                                               (float4*)h_a, (float4*)out);

    float* cur = h_a;
    float* nxt = h_b;
    for (int layer = 0; layer < 3; ++layer) {
        zero_kernel<<<ew_blocks, 256, 0, stream>>>((float4*)nxt, n4);
        // 4096 blocks x 256 thr = 16384 waves, grid-stride over 6M edges
        spmm_scatter<<<4096, 256, 0, stream>>>(edge_src, edge_dst, edge_val, cur, nxt);
        if (layer < 2) {
            add_kernel<<<ew_blocks, 256, 0, stream>>>((float4*)out, (const float4*)nxt, n4);
        } else {
            add_scale_kernel<<<ew_blocks, 256, 0, stream>>>((float4*)out, (const float4*)nxt,
                                                            n4, 0.25f);
        }
        float* t = cur; cur = nxt; nxt = t;
    }
}

// Round 3
// 1314.328 us; speedup vs baseline: 2.9656x; 2.9656x over previous
//
#include <hip/hip_runtime.h>

#define N_USERS 100000
#define M_ITEMS 50000
#define N_NODES 150000
#define N_EDGES 6000000
#define DIM 64

#define SCAN_TPB 1024
#define SCAN_NBLK ((N_NODES + SCAN_TPB - 1) / SCAN_TPB)   // 147

// ---------------- init: h_cur = acc = concat(user_emb, item_emb); zero counts ---
__global__ void init_kernel(const float4* __restrict__ user_emb,
                            const float4* __restrict__ item_emb,
                            float4* __restrict__ h_cur,
                            float4* __restrict__ acc,
                            int* __restrict__ counts) {
    const int n_user4 = N_USERS * DIM / 4;   // 1,600,000
    const int n_tot4  = N_NODES * DIM / 4;   // 2,400,000
    int i = blockIdx.x * blockDim.x + threadIdx.x;
    if (i < n_tot4) {
        float4 v = (i < n_user4) ? user_emb[i] : item_emb[i - n_user4];
        h_cur[i] = v;
        acc[i]   = v;
    }
    if (i < N_NODES) counts[i] = 0;
}

// ---------------- histogram of dst --------------------------------------------
__global__ void hist_kernel(const int* __restrict__ dst, int* __restrict__ counts) {
    int e = blockIdx.x * blockDim.x + threadIdx.x;
    if (e < N_EDGES) atomicAdd(&counts[dst[e]], 1);
}

// ---------------- scan level 1: per-block exclusive scan of counts -> row_ptr --
__global__ __launch_bounds__(SCAN_TPB) void scan1_kernel(const int* __restrict__ counts,
                                                         int* __restrict__ row_ptr,
                                                         int* __restrict__ blk_sums) {
    __shared__ int lds[SCAN_TPB];
    int tid = threadIdx.x;
    int i = blockIdx.x * SCAN_TPB + tid;
    int v = (i < N_NODES) ? counts[i] : 0;
    lds[tid] = v;
    __syncthreads();
    for (int off = 1; off < SCAN_TPB; off <<= 1) {
        int t = (tid >= off) ? lds[tid - off] : 0;
        __syncthreads();
        lds[tid] += t;
        __syncthreads();
    }
    if (i < N_NODES) row_ptr[i] = lds[tid] - v;           // exclusive within block
    if (tid == SCAN_TPB - 1) blk_sums[blockIdx.x] = lds[tid];
}

// ---------------- scan level 2: exclusive scan of 147 block sums ---------------
__global__ __launch_bounds__(256) void scan2_kernel(const int* __restrict__ blk_sums,
                                                    int* __restrict__ blk_offs) {
    __shared__ int lds[256];
    int tid = threadIdx.x;
    int v = (tid < SCAN_NBLK) ? blk_sums[tid] : 0;
    lds[tid] = v;
    __syncthreads();
    for (int off = 1; off < 256; off <<= 1) {
        int t = (tid >= off) ? lds[tid - off] : 0;
        __syncthreads();
        lds[tid] += t;
        __syncthreads();
    }
    if (tid < SCAN_NBLK) blk_offs[tid] = lds[tid] - v;    // exclusive
}

// ---------------- scan level 3: add offsets; zero fill cursors -----------------
__global__ __launch_bounds__(SCAN_TPB) void scan3_kernel(int* __restrict__ row_ptr,
                                                         const int* __restrict__ blk_offs,
                                                         int* __restrict__ counts) {
    int i = blockIdx.x * SCAN_TPB + threadIdx.x;
    if (i < N_NODES) {
        row_ptr[i] += blk_offs[blockIdx.x];
        counts[i] = 0;                                    // reuse counts as fill cursors
    }
    if (i == 0) row_ptr[N_NODES] = N_EDGES;
}

// ---------------- fill CSR: counting-sort edges by dst -------------------------
__global__ void fill_kernel(const int* __restrict__ src,
                            const int* __restrict__ dst,
                            const float* __restrict__ val,
                            const int* __restrict__ row_ptr,
                            int* __restrict__ cursors,
                            int2* __restrict__ csr) {
    int e = blockIdx.x * blockDim.x + threadIdx.x;
    if (e < N_EDGES) {
        int d = dst[e];
        int pos = row_ptr[d] + atomicAdd(&cursors[d], 1);
        csr[pos] = make_int2(src[e], __float_as_int(val[e]));
    }
}

// ---------------- pull SpMM: one wave per node, lane = dim ---------------------
// last=0: h_out = A*h_in; acc += h_out.   last=1: acc = (acc + A*h_in) * 0.25
__global__ __launch_bounds__(256) void spmm_pull(const int* __restrict__ row_ptr,
                                                 const int2* __restrict__ csr,
                                                 const float* __restrict__ h_in,
                                                 float* __restrict__ h_out,
                                                 float* __restrict__ acc,
                                                 int last) {
    int lane = threadIdx.x & 63;
    int node = (blockIdx.x * blockDim.x + threadIdx.x) >> 6;
    if (node >= N_NODES) return;
    int beg = row_ptr[node];
    int end = row_ptr[node + 1];
    float s = 0.f;
    int j = beg;
    for (; j + 4 <= end; j += 4) {
        int2 e0 = csr[j];
        int2 e1 = csr[j + 1];
        int2 e2 = csr[j + 2];
        int2 e3 = csr[j + 3];
        float a0 = h_in[(size_t)e0.x * DIM + lane];
        float a1 = h_in[(size_t)e1.x * DIM + lane];
        float a2 = h_in[(size_t)e2.x * DIM + lane];
        float a3 = h_in[(size_t)e3.x * DIM + lane];
        s += a0 * __int_as_float(e0.y);
        s += a1 * __int_as_float(e1.y);
        s += a2 * __int_as_float(e2.y);
        s += a3 * __int_as_float(e3.y);
    }
    for (; j < end; ++j) {
        int2 e = csr[j];
        s += h_in[(size_t)e.x * DIM + lane] * __int_as_float(e.y);
    }
    size_t o = (size_t)node * DIM + lane;
    if (!last) {
        h_out[o] = s;
        acc[o] += s;
    } else {
        acc[o] = (acc[o] + s) * 0.25f;
    }
}

extern "C" void kernel_launch(void* const* d_in, const int* in_sizes, int n_in,
                              void* d_out, int out_size, void* d_ws, size_t ws_size,
                              hipStream_t stream) {
    const float* user_emb = (const float*)d_in[0];
    const float* item_emb = (const float*)d_in[1];
    const int*   edge_src = (const int*)d_in[2];
    const int*   edge_dst = (const int*)d_in[3];
    const float* edge_val = (const float*)d_in[4];
    float* out = (float*)d_out;                       // acc lives here

    // workspace layout
    float* h_a     = (float*)d_ws;                            // 9.6M floats
    float* h_b     = h_a + (size_t)N_NODES * DIM;             // 9.6M floats
    int*   counts  = (int*)(h_b + (size_t)N_NODES * DIM);     // 150k (also fill cursors)
    int*   row_ptr = counts + N_NODES;                        // 150,001
    int*   blk_sums= row_ptr + N_NODES + 1;                   // 256
    int*   blk_offs= blk_sums + 256;                          // 256
    int2*  csr     = (int2*)(blk_offs + 256);                 // 6M int2 (48 MB)

    const int n4 = N_NODES * DIM / 4;                 // 2,400,000
    const int ew_blocks   = (n4 + 255) / 256;
    const int edge_blocks = (N_EDGES + 255) / 256;
    const int pull_blocks = (N_NODES + 3) / 4;        // 4 waves (nodes) per block

    // ---- build CSR (once per call, used by all 3 layers) ----
    init_kernel<<<ew_blocks, 256, 0, stream>>>((const float4*)user_emb,
                                               (const float4*)item_emb,
                                               (float4*)h_a, (float4*)out, counts);
    hist_kernel<<<edge_blocks, 256, 0, stream>>>(edge_dst, counts);
    scan1_kernel<<<SCAN_NBLK, SCAN_TPB, 0, stream>>>(counts, row_ptr, blk_sums);
    scan2_kernel<<<1, 256, 0, stream>>>(blk_sums, blk_offs);
    scan3_kernel<<<SCAN_NBLK, SCAN_TPB, 0, stream>>>(row_ptr, blk_offs, counts);
    fill_kernel<<<edge_blocks, 256, 0, stream>>>(edge_src, edge_dst, edge_val,
                                                 row_ptr, counts, csr);

    // ---- 3 pull layers, epilogues fused ----
    spmm_pull<<<pull_blocks, 256, 0, stream>>>(row_ptr, csr, h_a, h_b, out, 0);
    spmm_pull<<<pull_blocks, 256, 0, stream>>>(row_ptr, csr, h_b, h_a, out, 0);
    spmm_pull<<<pull_blocks, 256, 0, stream>>>(row_ptr, csr, h_a, h_b, out, 1);
}

// Round 4
// 1240.409 us; speedup vs baseline: 3.1423x; 1.0596x over previous
//
#include <hip/hip_runtime.h>
#include <hip/hip_fp16.h>

#define N_USERS 100000
#define M_ITEMS 50000
#define N_NODES 150000
#define N_EDGES 6000000
#define DIM 64

#define SCAN_TPB 1024
#define SCAN_NBLK ((N_NODES + SCAN_TPB - 1) / SCAN_TPB)   // 147

#define VAL_BITS 14
#define VAL_MASK ((1u << VAL_BITS) - 1u)                  // 16383
#define VAL_SCALE 16383.0f
#define VAL_INV   (1.0f / 16383.0f)

// ---- init: h_cur(fp16) = acc(fp32) = concat(user_emb, item_emb); zero counts ---
__global__ void init_kernel(const float4* __restrict__ user_emb,
                            const float4* __restrict__ item_emb,
                            ushort4* __restrict__ h_cur,   // 4 halves packed
                            float4* __restrict__ acc,
                            int* __restrict__ counts) {
    const int n_user4 = N_USERS * DIM / 4;   // 1,600,000
    const int n_tot4  = N_NODES * DIM / 4;   // 2,400,000
    int i = blockIdx.x * blockDim.x + threadIdx.x;
    if (i < n_tot4) {
        float4 v = (i < n_user4) ? user_emb[i] : item_emb[i - n_user4];
        ushort4 hv;
        hv.x = __half_as_ushort(__float2half_rn(v.x));
        hv.y = __half_as_ushort(__float2half_rn(v.y));
        hv.z = __half_as_ushort(__float2half_rn(v.z));
        hv.w = __half_as_ushort(__float2half_rn(v.w));
        h_cur[i] = hv;
        acc[i]   = v;
    }
    if (i < N_NODES) counts[i] = 0;
}

// ---------------- histogram of dst --------------------------------------------
__global__ void hist_kernel(const int* __restrict__ dst, int* __restrict__ counts) {
    int e = blockIdx.x * blockDim.x + threadIdx.x;
    if (e < N_EDGES) atomicAdd(&counts[dst[e]], 1);
}

// ---------------- scan level 1: per-block exclusive scan of counts -> row_ptr --
__global__ __launch_bounds__(SCAN_TPB) void scan1_kernel(const int* __restrict__ counts,
                                                         int* __restrict__ row_ptr,
                                                         int* __restrict__ blk_sums) {
    __shared__ int lds[SCAN_TPB];
    int tid = threadIdx.x;
    int i = blockIdx.x * SCAN_TPB + tid;
    int v = (i < N_NODES) ? counts[i] : 0;
    lds[tid] = v;
    __syncthreads();
    for (int off = 1; off < SCAN_TPB; off <<= 1) {
        int t = (tid >= off) ? lds[tid - off] : 0;
        __syncthreads();
        lds[tid] += t;
        __syncthreads();
    }
    if (i < N_NODES) row_ptr[i] = lds[tid] - v;           // exclusive within block
    if (tid == SCAN_TPB - 1) blk_sums[blockIdx.x] = lds[tid];
}

// ---------------- scan level 2: exclusive scan of 147 block sums ---------------
__global__ __launch_bounds__(256) void scan2_kernel(const int* __restrict__ blk_sums,
                                                    int* __restrict__ blk_offs) {
    __shared__ int lds[256];
    int tid = threadIdx.x;
    int v = (tid < SCAN_NBLK) ? blk_sums[tid] : 0;
    lds[tid] = v;
    __syncthreads();
    for (int off = 1; off < 256; off <<= 1) {
        int t = (tid >= off) ? lds[tid - off] : 0;
        __syncthreads();
        lds[tid] += t;
        __syncthreads();
    }
    if (tid < SCAN_NBLK) blk_offs[tid] = lds[tid] - v;    // exclusive
}

// ---------------- scan level 3: add offsets; zero fill cursors -----------------
__global__ __launch_bounds__(SCAN_TPB) void scan3_kernel(int* __restrict__ row_ptr,
                                                         const int* __restrict__ blk_offs,
                                                         int* __restrict__ counts) {
    int i = blockIdx.x * SCAN_TPB + threadIdx.x;
    if (i < N_NODES) {
        row_ptr[i] += blk_offs[blockIdx.x];
        counts[i] = 0;                                    // reuse counts as fill cursors
    }
    if (i == 0) row_ptr[N_NODES] = N_EDGES;
}

// ---------------- fill CSR: counting-sort edges by dst; 4B packed entry --------
// entry = (src << 14) | round(val * 16383)
__global__ void fill_kernel(const int* __restrict__ src,
                            const int* __restrict__ dst,
                            const float* __restrict__ val,
                            const int* __restrict__ row_ptr,
                            int* __restrict__ cursors,
                            unsigned int* __restrict__ csr) {
    int e = blockIdx.x * blockDim.x + threadIdx.x;
    if (e < N_EDGES) {
        int d = dst[e];
        int pos = row_ptr[d] + atomicAdd(&cursors[d], 1);
        unsigned int q = __float2uint_rn(val[e] * VAL_SCALE);
        csr[pos] = ((unsigned int)src[e] << VAL_BITS) | q;
    }
}

// ---------------- pull SpMM: one wave per node, lane = dim ---------------------
// last=0: h_out = fp16(A*h_in); acc += A*h_in.   last=1: acc = (acc + A*h_in)*0.25
__global__ __launch_bounds__(256) void spmm_pull(const int* __restrict__ row_ptr,
                                                 const unsigned int* __restrict__ csr,
                                                 const __half* __restrict__ h_in,
                                                 __half* __restrict__ h_out,
                                                 float* __restrict__ acc,
                                                 int last) {
    int lane = threadIdx.x & 63;
    int node = (blockIdx.x * blockDim.x + threadIdx.x) >> 6;
    if (node >= N_NODES) return;
    int beg = row_ptr[node];
    int end = row_ptr[node + 1];
    float s = 0.f;
    int j = beg;
    for (; j + 8 <= end; j += 8) {
        unsigned int p0 = __builtin_nontemporal_load(&csr[j]);
        unsigned int p1 = __builtin_nontemporal_load(&csr[j + 1]);
        unsigned int p2 = __builtin_nontemporal_load(&csr[j + 2]);
        unsigned int p3 = __builtin_nontemporal_load(&csr[j + 3]);
        unsigned int p4 = __builtin_nontemporal_load(&csr[j + 4]);
        unsigned int p5 = __builtin_nontemporal_load(&csr[j + 5]);
        unsigned int p6 = __builtin_nontemporal_load(&csr[j + 6]);
        unsigned int p7 = __builtin_nontemporal_load(&csr[j + 7]);
        float a0 = __half2float(h_in[(size_t)(p0 >> VAL_BITS) * DIM + lane]);
        float a1 = __half2float(h_in[(size_t)(p1 >> VAL_BITS) * DIM + lane]);
        float a2 = __half2float(h_in[(size_t)(p2 >> VAL_BITS) * DIM + lane]);
        float a3 = __half2float(h_in[(size_t)(p3 >> VAL_BITS) * DIM + lane]);
        float a4 = __half2float(h_in[(size_t)(p4 >> VAL_BITS) * DIM + lane]);
        float a5 = __half2float(h_in[(size_t)(p5 >> VAL_BITS) * DIM + lane]);
        float a6 = __half2float(h_in[(size_t)(p6 >> VAL_BITS) * DIM + lane]);
        float a7 = __half2float(h_in[(size_t)(p7 >> VAL_BITS) * DIM + lane]);
        s += a0 * ((float)(p0 & VAL_MASK) * VAL_INV);
        s += a1 * ((float)(p1 & VAL_MASK) * VAL_INV);
        s += a2 * ((float)(p2 & VAL_MASK) * VAL_INV);
        s += a3 * ((float)(p3 & VAL_MASK) * VAL_INV);
        s += a4 * ((float)(p4 & VAL_MASK) * VAL_INV);
        s += a5 * ((float)(p5 & VAL_MASK) * VAL_INV);
        s += a6 * ((float)(p6 & VAL_MASK) * VAL_INV);
        s += a7 * ((float)(p7 & VAL_MASK) * VAL_INV);
    }
    for (; j < end; ++j) {
        unsigned int p = __builtin_nontemporal_load(&csr[j]);
        float a = __half2float(h_in[(size_t)(p >> VAL_BITS) * DIM + lane]);
        s += a * ((float)(p & VAL_MASK) * VAL_INV);
    }
    size_t o = (size_t)node * DIM + lane;
    if (!last) {
        h_out[o] = __float2half_rn(s);
        acc[o] += s;
    } else {
        acc[o] = (acc[o] + s) * 0.25f;
    }
}

extern "C" void kernel_launch(void* const* d_in, const int* in_sizes, int n_in,
                              void* d_out, int out_size, void* d_ws, size_t ws_size,
                              hipStream_t stream) {
    const float* user_emb = (const float*)d_in[0];
    const float* item_emb = (const float*)d_in[1];
    const int*   edge_src = (const int*)d_in[2];
    const int*   edge_dst = (const int*)d_in[3];
    const float* edge_val = (const float*)d_in[4];
    float* out = (float*)d_out;                       // acc lives here

    // workspace layout
    __half* h_a    = (__half*)d_ws;                            // 9.6M halfs (19.2MB)
    __half* h_b    = h_a + (size_t)N_NODES * DIM;              // 9.6M halfs
    int*   counts  = (int*)(h_b + (size_t)N_NODES * DIM);      // 150k (also cursors)
    int*   row_ptr = counts + N_NODES;                         // 150,001
    int*   blk_sums= row_ptr + N_NODES + 1;                    // 256
    int*   blk_offs= blk_sums + 256;                           // 256
    unsigned int* csr = (unsigned int*)(blk_offs + 256);       // 6M uint (24MB)

    const int n4 = N_NODES * DIM / 4;                 // 2,400,000
    const int ew_blocks   = (n4 + 255) / 256;
    const int edge_blocks = (N_EDGES + 255) / 256;
    const int pull_blocks = (N_NODES + 3) / 4;        // 4 waves (nodes) per block

    // ---- build CSR (once per call, used by all 3 layers) ----
    init_kernel<<<ew_blocks, 256, 0, stream>>>((const float4*)user_emb,
                                               (const float4*)item_emb,
                                               (ushort4*)h_a, (float4*)out, counts);
    hist_kernel<<<edge_blocks, 256, 0, stream>>>(edge_dst, counts);
    scan1_kernel<<<SCAN_NBLK, SCAN_TPB, 0, stream>>>(counts, row_ptr, blk_sums);
    scan2_kernel<<<1, 256, 0, stream>>>(blk_sums, blk_offs);
    scan3_kernel<<<SCAN_NBLK, SCAN_TPB, 0, stream>>>(row_ptr, blk_offs, counts);
    fill_kernel<<<edge_blocks, 256, 0, stream>>>(edge_src, edge_dst, edge_val,
                                                 row_ptr, counts, csr);

    // ---- 3 pull layers, epilogues fused ----
    spmm_pull<<<pull_blocks, 256, 0, stream>>>(row_ptr, csr, h_a, h_b, out, 0);
    spmm_pull<<<pull_blocks, 256, 0, stream>>>(row_ptr, csr, h_b, h_a, out, 0);
    spmm_pull<<<pull_blocks, 256, 0, stream>>>(row_ptr, csr, h_a, h_b, out, 1);
}

// Round 5
// 1010.001 us; speedup vs baseline: 3.8592x; 1.2281x over previous
//
#include <hip/hip_runtime.h>
#include <hip/hip_fp16.h>

#define N_USERS 100000
#define M_ITEMS 50000
#define N_NODES 150000
#define N_EDGES 6000000
#define DIM 64

#define SCAN_TPB 1024
#define SCAN_NBLK ((N_NODES + SCAN_TPB - 1) / SCAN_TPB)   // 147

#define VAL_BITS 14
#define VAL_MASK ((1u << VAL_BITS) - 1u)                  // 16383
#define VAL_SCALE 16383.0f
#define VAL_INV   (1.0f / 16383.0f)

// ---- init: h_cur(fp16) = acc(fp32) = concat(user_emb, item_emb); zero counts ---
__global__ void init_kernel(const float4* __restrict__ user_emb,
                            const float4* __restrict__ item_emb,
                            ushort4* __restrict__ h_cur,   // 4 halves packed
                            float4* __restrict__ acc,
                            int* __restrict__ counts) {
    const int n_user4 = N_USERS * DIM / 4;   // 1,600,000
    const int n_tot4  = N_NODES * DIM / 4;   // 2,400,000
    int i = blockIdx.x * blockDim.x + threadIdx.x;
    if (i < n_tot4) {
        float4 v = (i < n_user4) ? user_emb[i] : item_emb[i - n_user4];
        ushort4 hv;
        hv.x = __half_as_ushort(__float2half_rn(v.x));
        hv.y = __half_as_ushort(__float2half_rn(v.y));
        hv.z = __half_as_ushort(__float2half_rn(v.z));
        hv.w = __half_as_ushort(__float2half_rn(v.w));
        h_cur[i] = hv;
        acc[i]   = v;
    }
    if (i < N_NODES) counts[i] = 0;
}

// ---------------- histogram of dst --------------------------------------------
__global__ void hist_kernel(const int* __restrict__ dst, int* __restrict__ counts) {
    int e = blockIdx.x * blockDim.x + threadIdx.x;
    if (e < N_EDGES) atomicAdd(&counts[dst[e]], 1);
}

// ---------------- scan level 1: per-block exclusive scan of counts -> row_ptr --
__global__ __launch_bounds__(SCAN_TPB) void scan1_kernel(const int* __restrict__ counts,
                                                         int* __restrict__ row_ptr,
                                                         int* __restrict__ blk_sums) {
    __shared__ int lds[SCAN_TPB];
    int tid = threadIdx.x;
    int i = blockIdx.x * SCAN_TPB + tid;
    int v = (i < N_NODES) ? counts[i] : 0;
    lds[tid] = v;
    __syncthreads();
    for (int off = 1; off < SCAN_TPB; off <<= 1) {
        int t = (tid >= off) ? lds[tid - off] : 0;
        __syncthreads();
        lds[tid] += t;
        __syncthreads();
    }
    if (i < N_NODES) row_ptr[i] = lds[tid] - v;           // exclusive within block
    if (tid == SCAN_TPB - 1) blk_sums[blockIdx.x] = lds[tid];
}

// ---------------- scan level 2: exclusive scan of 147 block sums ---------------
__global__ __launch_bounds__(256) void scan2_kernel(const int* __restrict__ blk_sums,
                                                    int* __restrict__ blk_offs) {
    __shared__ int lds[256];
    int tid = threadIdx.x;
    int v = (tid < SCAN_NBLK) ? blk_sums[tid] : 0;
    lds[tid] = v;
    __syncthreads();
    for (int off = 1; off < 256; off <<= 1) {
        int t = (tid >= off) ? lds[tid - off] : 0;
        __syncthreads();
        lds[tid] += t;
        __syncthreads();
    }
    if (tid < SCAN_NBLK) blk_offs[tid] = lds[tid] - v;    // exclusive
}

// ---------------- scan level 3: add offsets; zero fill cursors -----------------
__global__ __launch_bounds__(SCAN_TPB) void scan3_kernel(int* __restrict__ row_ptr,
                                                         const int* __restrict__ blk_offs,
                                                         int* __restrict__ counts) {
    int i = blockIdx.x * SCAN_TPB + threadIdx.x;
    if (i < N_NODES) {
        row_ptr[i] += blk_offs[blockIdx.x];
        counts[i] = 0;                                    // reuse counts as fill cursors
    }
    if (i == 0) row_ptr[N_NODES] = N_EDGES;
}

// ---------------- fill CSR: counting-sort edges by dst; 4B packed entry --------
// entry = (src << 14) | round(val * 16383)
__global__ void fill_kernel(const int* __restrict__ src,
                            const int* __restrict__ dst,
                            const float* __restrict__ val,
                            const int* __restrict__ row_ptr,
                            int* __restrict__ cursors,
                            unsigned int* __restrict__ csr) {
    int e = blockIdx.x * blockDim.x + threadIdx.x;
    if (e < N_EDGES) {
        int d = dst[e];
        int pos = row_ptr[d] + atomicAdd(&cursors[d], 1);
        unsigned int q = __float2uint_rn(val[e] * VAL_SCALE);
        csr[pos] = ((unsigned int)src[e] << VAL_BITS) | q;
    }
}

// ---------------- pull SpMM: one wave per node; 8 edge-groups x 8 dim-lanes ----
// Group g (lane>>3) processes edges beg+g, beg+g+8, ...; lane sub (lane&7)
// holds dims [sub*8, sub*8+8) as 8 fp32 accumulators. One 16B uint4 gather per
// lane per edge => each wave gather instruction moves 8 edges x 128B = 1024B.
// last=0: h_out = fp16(A*h_in); acc += A*h_in.   last=1: acc = (acc + A*h_in)*0.25
__global__ __launch_bounds__(256) void spmm_pull(const int* __restrict__ row_ptr,
                                                 const unsigned int* __restrict__ csr,
                                                 const __half* __restrict__ h_in,
                                                 __half* __restrict__ h_out,
                                                 float* __restrict__ acc,
                                                 int last) {
    int lane = threadIdx.x & 63;
    int g    = lane >> 3;
    int sub  = lane & 7;
    int node = (blockIdx.x * blockDim.x + threadIdx.x) >> 6;
    if (node >= N_NODES) return;
    int beg = row_ptr[node];
    int end = row_ptr[node + 1];

    float s0 = 0.f, s1 = 0.f, s2 = 0.f, s3 = 0.f;
    float s4 = 0.f, s5 = 0.f, s6 = 0.f, s7 = 0.f;

    int j = beg + g;
    // unroll x2: two independent gathers in flight
    for (; j + 8 < end; j += 16) {
        unsigned int p0 = __builtin_nontemporal_load(&csr[j]);
        unsigned int p1 = __builtin_nontemporal_load(&csr[j + 8]);
        const uint4* r0p = (const uint4*)(h_in + (size_t)(p0 >> VAL_BITS) * DIM) + sub;
        const uint4* r1p = (const uint4*)(h_in + (size_t)(p1 >> VAL_BITS) * DIM) + sub;
        uint4 r0 = *r0p;
        uint4 r1 = *r1p;
        float w0 = (float)(p0 & VAL_MASK) * VAL_INV;
        float w1 = (float)(p1 & VAL_MASK) * VAL_INV;
        {
            float2 f0 = __half22float2(*(const __half2*)&r0.x);
            float2 f1 = __half22float2(*(const __half2*)&r0.y);
            float2 f2 = __half22float2(*(const __half2*)&r0.z);
            float2 f3 = __half22float2(*(const __half2*)&r0.w);
            s0 += w0 * f0.x; s1 += w0 * f0.y;
            s2 += w0 * f1.x; s3 += w0 * f1.y;
            s4 += w0 * f2.x; s5 += w0 * f2.y;
            s6 += w0 * f3.x; s7 += w0 * f3.y;
        }
        {
            float2 f0 = __half22float2(*(const __half2*)&r1.x);
            float2 f1 = __half22float2(*(const __half2*)&r1.y);
            float2 f2 = __half22float2(*(const __half2*)&r1.z);
            float2 f3 = __half22float2(*(const __half2*)&r1.w);
            s0 += w1 * f0.x; s1 += w1 * f0.y;
            s2 += w1 * f1.x; s3 += w1 * f1.y;
            s4 += w1 * f2.x; s5 += w1 * f2.y;
            s6 += w1 * f3.x; s7 += w1 * f3.y;
        }
    }
    if (j < end) {
        unsigned int p0 = __builtin_nontemporal_load(&csr[j]);
        const uint4* r0p = (const uint4*)(h_in + (size_t)(p0 >> VAL_BITS) * DIM) + sub;
        uint4 r0 = *r0p;
        float w0 = (float)(p0 & VAL_MASK) * VAL_INV;
        float2 f0 = __half22float2(*(const __half2*)&r0.x);
        float2 f1 = __half22float2(*(const __half2*)&r0.y);
        float2 f2 = __half22float2(*(const __half2*)&r0.z);
        float2 f3 = __half22float2(*(const __half2*)&r0.w);
        s0 += w0 * f0.x; s1 += w0 * f0.y;
        s2 += w0 * f1.x; s3 += w0 * f1.y;
        s4 += w0 * f2.x; s5 += w0 * f2.y;
        s6 += w0 * f3.x; s7 += w0 * f3.y;
    }

    // reduce across the 8 edge-groups (stride 8, 16, 32); result lands in g==0
    #pragma unroll
    for (int d = 8; d < 64; d <<= 1) {
        s0 += __shfl_down(s0, d, 64);
        s1 += __shfl_down(s1, d, 64);
        s2 += __shfl_down(s2, d, 64);
        s3 += __shfl_down(s3, d, 64);
        s4 += __shfl_down(s4, d, 64);
        s5 += __shfl_down(s5, d, 64);
        s6 += __shfl_down(s6, d, 64);
        s7 += __shfl_down(s7, d, 64);
    }

    if (g == 0) {
        size_t o = (size_t)node * DIM + (size_t)sub * 8;
        float4* ap = (float4*)(acc + o);
        float4 x0 = ap[0];
        float4 x1 = ap[1];
        if (!last) {
            // h_out row store: 8 halves = 16B per lane, 8 lanes = 128B row
            __half2 q0 = __floats2half2_rn(s0, s1);
            __half2 q1 = __floats2half2_rn(s2, s3);
            __half2 q2 = __floats2half2_rn(s4, s5);
            __half2 q3 = __floats2half2_rn(s6, s7);
            uint4 w4;
            w4.x = *(const unsigned int*)&q0;
            w4.y = *(const unsigned int*)&q1;
            w4.z = *(const unsigned int*)&q2;
            w4.w = *(const unsigned int*)&q3;
            *(uint4*)(h_out + o) = w4;
            x0.x += s0; x0.y += s1; x0.z += s2; x0.w += s3;
            x1.x += s4; x1.y += s5; x1.z += s6; x1.w += s7;
        } else {
            x0.x = (x0.x + s0) * 0.25f; x0.y = (x0.y + s1) * 0.25f;
            x0.z = (x0.z + s2) * 0.25f; x0.w = (x0.w + s3) * 0.25f;
            x1.x = (x1.x + s4) * 0.25f; x1.y = (x1.y + s5) * 0.25f;
            x1.z = (x1.z + s6) * 0.25f; x1.w = (x1.w + s7) * 0.25f;
        }
        ap[0] = x0;
        ap[1] = x1;
    }
}

extern "C" void kernel_launch(void* const* d_in, const int* in_sizes, int n_in,
                              void* d_out, int out_size, void* d_ws, size_t ws_size,
                              hipStream_t stream) {
    const float* user_emb = (const float*)d_in[0];
    const float* item_emb = (const float*)d_in[1];
    const int*   edge_src = (const int*)d_in[2];
    const int*   edge_dst = (const int*)d_in[3];
    const float* edge_val = (const float*)d_in[4];
    float* out = (float*)d_out;                       // acc lives here

    // workspace layout
    __half* h_a    = (__half*)d_ws;                            // 9.6M halfs (19.2MB)
    __half* h_b    = h_a + (size_t)N_NODES * DIM;              // 9.6M halfs
    int*   counts  = (int*)(h_b + (size_t)N_NODES * DIM);      // 150k (also cursors)
    int*   row_ptr = counts + N_NODES;                         // 150,001
    int*   blk_sums= row_ptr + N_NODES + 1;                    // 256
    int*   blk_offs= blk_sums + 256;                           // 256
    unsigned int* csr = (unsigned int*)(blk_offs + 256);       // 6M uint (24MB)

    const int n4 = N_NODES * DIM / 4;                 // 2,400,000
    const int ew_blocks   = (n4 + 255) / 256;
    const int edge_blocks = (N_EDGES + 255) / 256;
    const int pull_blocks = (N_NODES + 3) / 4;        // 4 waves (nodes) per block

    // ---- build CSR (once per call, used by all 3 layers) ----
    init_kernel<<<ew_blocks, 256, 0, stream>>>((const float4*)user_emb,
                                               (const float4*)item_emb,
                                               (ushort4*)h_a, (float4*)out, counts);
    hist_kernel<<<edge_blocks, 256, 0, stream>>>(edge_dst, counts);
    scan1_kernel<<<SCAN_NBLK, SCAN_TPB, 0, stream>>>(counts, row_ptr, blk_sums);
    scan2_kernel<<<1, 256, 0, stream>>>(blk_sums, blk_offs);
    scan3_kernel<<<SCAN_NBLK, SCAN_TPB, 0, stream>>>(row_ptr, blk_offs, counts);
    fill_kernel<<<edge_blocks, 256, 0, stream>>>(edge_src, edge_dst, edge_val,
                                                 row_ptr, counts, csr);

    // ---- 3 pull layers, epilogues fused ----
    spmm_pull<<<pull_blocks, 256, 0, stream>>>(row_ptr, csr, h_a, h_b, out, 0);
    spmm_pull<<<pull_blocks, 256, 0, stream>>>(row_ptr, csr, h_b, h_a, out, 0);
    spmm_pull<<<pull_blocks, 256, 0, stream>>>(row_ptr, csr, h_a, h_b, out, 1);
}

// Round 6
// 956.136 us; speedup vs baseline: 4.0766x; 1.0563x over previous
//
#include <hip/hip_runtime.h>
#include <hip/hip_fp16.h>

#define N_USERS 100000
#define M_ITEMS 50000
#define N_NODES 150000
#define N_EDGES 6000000
#define DIM 64

#define VAL_BITS 14
#define VAL_MASK ((1u << VAL_BITS) - 1u)                  // 16383
#define VAL_SCALE 16383.0f
#define VAL_INV   (1.0f / 16383.0f)

#define N_BKT   ((N_NODES + 255) >> 8)                    // 586 buckets, 256 nodes each
#define N_GRP   8                                         // sub-buckets per bucket (~XCD)
#define CAPG    1792                                      // slots per sub-bucket (mean 1280, +14 sigma)
#define CAP     12288                                     // LDS staging slots (mean 10240, +20 sigma)
#define OFLOW_CAP 4096

// ---- init: h_cur(fp16) = acc(fp32) = concat(user_emb, item_emb); zero cursors --
__global__ void init_kernel(const float4* __restrict__ user_emb,
                            const float4* __restrict__ item_emb,
                            ushort4* __restrict__ h_cur,
                            float4* __restrict__ acc,
                            int* __restrict__ cursors) {   // N_BKT*N_GRP + 1 (oflow cnt)
    const int n_user4 = N_USERS * DIM / 4;
    const int n_tot4  = N_NODES * DIM / 4;
    int i = blockIdx.x * blockDim.x + threadIdx.x;
    if (i < n_tot4) {
        float4 v = (i < n_user4) ? user_emb[i] : item_emb[i - n_user4];
        ushort4 hv;
        hv.x = __half_as_ushort(__float2half_rn(v.x));
        hv.y = __half_as_ushort(__float2half_rn(v.y));
        hv.z = __half_as_ushort(__float2half_rn(v.z));
        hv.w = __half_as_ushort(__float2half_rn(v.w));
        h_cur[i] = hv;
        acc[i]   = v;
    }
    if (i < N_BKT * N_GRP + 1) cursors[i] = 0;
}

// ---- partition: edges -> 8 XCD-group sub-buckets per dst-bucket ----------------
// payload = (src << 14) | round(val * 16383)   (18 + 14 = 32 bits)
__global__ void partition_kernel(const int* __restrict__ src,
                                 const int* __restrict__ dst,
                                 const float* __restrict__ val,
                                 int* __restrict__ cursors,       // [N_BKT*N_GRP]
                                 int* __restrict__ oflow_cnt,     // [1]
                                 uint2* __restrict__ bucket_mem,  // [N_BKT*N_GRP*CAPG]
                                 uint2* __restrict__ oflow) {     // [OFLOW_CAP]
    int e = blockIdx.x * blockDim.x + threadIdx.x;
    if (e >= N_EDGES) return;
    int d = dst[e];
    int b = d >> 8;
    int grp = blockIdx.x & (N_GRP - 1);
    unsigned int q = __float2uint_rn(val[e] * VAL_SCALE);
    unsigned int payload = ((unsigned int)src[e] << VAL_BITS) | q;
    int sb = b * N_GRP + grp;
    int slot = atomicAdd(&cursors[sb], 1);
    if (slot < CAPG) {
        bucket_mem[(size_t)sb * CAPG + slot] = make_uint2((unsigned int)d, payload);
    } else {
        int o = atomicAdd(oflow_cnt, 1);
        if (o < OFLOW_CAP) oflow[o] = make_uint2((unsigned int)d, payload);
    }
}

// ---- scan bucket totals -> bucket_base (exclusive); one block ------------------
__global__ __launch_bounds__(1024) void bucket_scan_kernel(const int* __restrict__ cursors,
                                                           int* __restrict__ bucket_base,
                                                           int* __restrict__ row_ptr) {
    __shared__ int lds[1024];
    int tid = threadIdx.x;
    int v = 0;
    if (tid < N_BKT) {
        #pragma unroll
        for (int g = 0; g < N_GRP; ++g) v += cursors[tid * N_GRP + g];
    }
    lds[tid] = v;
    __syncthreads();
    for (int off = 1; off < 1024; off <<= 1) {
        int t = (tid >= off) ? lds[tid - off] : 0;
        __syncthreads();
        lds[tid] += t;
        __syncthreads();
    }
    if (tid < N_BKT) bucket_base[tid] = lds[tid] - v;     // exclusive
    if (tid == 0) {
        bucket_base[N_BKT] = N_EDGES;
        row_ptr[N_NODES] = N_EDGES;
    }
}

// ---- bucket sort: one block per bucket; LDS counting sort; coalesced CSR write -
__global__ __launch_bounds__(256) void bucket_sort_kernel(const int* __restrict__ cursors,
                                                          const int* __restrict__ oflow_cnt,
                                                          const uint2* __restrict__ bucket_mem,
                                                          const uint2* __restrict__ oflow,
                                                          const int* __restrict__ bucket_base,
                                                          int* __restrict__ row_ptr,
                                                          unsigned int* __restrict__ csr) {
    __shared__ unsigned int stage[CAP];    // 48 KB
    __shared__ int histo[256];
    __shared__ int cbase[256];
    __shared__ int lcur[256];

    int tid = threadIdx.x;
    int b = blockIdx.x;
    int node0 = b << 8;
    int region_base = bucket_base[b];
    int region_size = bucket_base[b + 1] - region_base;
    int on = min(*oflow_cnt, OFLOW_CAP);

    histo[tid] = 0;
    __syncthreads();

    // pass 1: histogram over the bucket's 256 local nodes
    for (int g = 0; g < N_GRP; ++g) {
        int sb = b * N_GRP + g;
        int ng = min(cursors[sb], CAPG);
        const uint2* base = bucket_mem + (size_t)sb * CAPG;
        for (int i = tid; i < ng; i += 256) {
            uint2 e = base[i];
            atomicAdd(&histo[e.x & 255u], 1);
        }
    }
    for (int i = tid; i < on; i += 256) {
        uint2 e = oflow[i];
        if ((int)(e.x >> 8) == b) atomicAdd(&histo[e.x & 255u], 1);
    }
    __syncthreads();

    // exclusive scan of 256 counts
    int v = histo[tid];
    cbase[tid] = v;
    __syncthreads();
    for (int off = 1; off < 256; off <<= 1) {
        int t = (tid >= off) ? cbase[tid - off] : 0;
        __syncthreads();
        cbase[tid] += t;
        __syncthreads();
    }
    int excl = cbase[tid] - v;
    lcur[tid] = excl;
    int node = node0 + tid;
    if (node < N_NODES) row_ptr[node] = region_base + excl;
    __syncthreads();

    // pass 2: place payloads into LDS staging at local positions
    for (int g = 0; g < N_GRP; ++g) {
        int sb = b * N_GRP + g;
        int ng = min(cursors[sb], CAPG);
        const uint2* base = bucket_mem + (size_t)sb * CAPG;
        for (int i = tid; i < ng; i += 256) {
            uint2 e = base[i];
            int pos = atomicAdd(&lcur[e.x & 255u], 1);
            if (pos < CAP) stage[pos] = e.y;
            else           csr[region_base + pos] = e.y;   // ~never
        }
    }
    for (int i = tid; i < on; i += 256) {
        uint2 e = oflow[i];
        if ((int)(e.x >> 8) == b) {
            int pos = atomicAdd(&lcur[e.x & 255u], 1);
            if (pos < CAP) stage[pos] = e.y;
            else           csr[region_base + pos] = e.y;
        }
    }
    __syncthreads();

    // stream the bucket's CSR region out, fully coalesced
    int lim = min(region_size, CAP);
    for (int i = tid; i < lim; i += 256) csr[region_base + i] = stage[i];
}

// ---------------- pull SpMM: one wave per node; 8 edge-groups x 8 dim-lanes ----
__global__ __launch_bounds__(256) void spmm_pull(const int* __restrict__ row_ptr,
                                                 const unsigned int* __restrict__ csr,
                                                 const __half* __restrict__ h_in,
                                                 __half* __restrict__ h_out,
                                                 float* __restrict__ acc,
                                                 int last) {
    int lane = threadIdx.x & 63;
    int g    = lane >> 3;
    int sub  = lane & 7;
    int node = (blockIdx.x * blockDim.x + threadIdx.x) >> 6;
    if (node >= N_NODES) return;
    int beg = row_ptr[node];
    int end = row_ptr[node + 1];

    float s0 = 0.f, s1 = 0.f, s2 = 0.f, s3 = 0.f;
    float s4 = 0.f, s5 = 0.f, s6 = 0.f, s7 = 0.f;

    int j = beg + g;
    for (; j + 8 < end; j += 16) {
        unsigned int p0 = __builtin_nontemporal_load(&csr[j]);
        unsigned int p1 = __builtin_nontemporal_load(&csr[j + 8]);
        const uint4* r0p = (const uint4*)(h_in + (size_t)(p0 >> VAL_BITS) * DIM) + sub;
        const uint4* r1p = (const uint4*)(h_in + (size_t)(p1 >> VAL_BITS) * DIM) + sub;
        uint4 r0 = *r0p;
        uint4 r1 = *r1p;
        float w0 = (float)(p0 & VAL_MASK) * VAL_INV;
        float w1 = (float)(p1 & VAL_MASK) * VAL_INV;
        {
            float2 f0 = __half22float2(*(const __half2*)&r0.x);
            float2 f1 = __half22float2(*(const __half2*)&r0.y);
            float2 f2 = __half22float2(*(const __half2*)&r0.z);
            float2 f3 = __half22float2(*(const __half2*)&r0.w);
            s0 += w0 * f0.x; s1 += w0 * f0.y;
            s2 += w0 * f1.x; s3 += w0 * f1.y;
            s4 += w0 * f2.x; s5 += w0 * f2.y;
            s6 += w0 * f3.x; s7 += w0 * f3.y;
        }
        {
            float2 f0 = __half22float2(*(const __half2*)&r1.x);
            float2 f1 = __half22float2(*(const __half2*)&r1.y);
            float2 f2 = __half22float2(*(const __half2*)&r1.z);
            float2 f3 = __half22float2(*(const __half2*)&r1.w);
            s0 += w1 * f0.x; s1 += w1 * f0.y;
            s2 += w1 * f1.x; s3 += w1 * f1.y;
            s4 += w1 * f2.x; s5 += w1 * f2.y;
            s6 += w1 * f3.x; s7 += w1 * f3.y;
        }
    }
    if (j < end) {
        unsigned int p0 = __builtin_nontemporal_load(&csr[j]);
        const uint4* r0p = (const uint4*)(h_in + (size_t)(p0 >> VAL_BITS) * DIM) + sub;
        uint4 r0 = *r0p;
        float w0 = (float)(p0 & VAL_MASK) * VAL_INV;
        float2 f0 = __half22float2(*(const __half2*)&r0.x);
        float2 f1 = __half22float2(*(const __half2*)&r0.y);
        float2 f2 = __half22float2(*(const __half2*)&r0.z);
        float2 f3 = __half22float2(*(const __half2*)&r0.w);
        s0 += w0 * f0.x; s1 += w0 * f0.y;
        s2 += w0 * f1.x; s3 += w0 * f1.y;
        s4 += w0 * f2.x; s5 += w0 * f2.y;
        s6 += w0 * f3.x; s7 += w0 * f3.y;
    }

    #pragma unroll
    for (int d = 8; d < 64; d <<= 1) {
        s0 += __shfl_down(s0, d, 64);
        s1 += __shfl_down(s1, d, 64);
        s2 += __shfl_down(s2, d, 64);
        s3 += __shfl_down(s3, d, 64);
        s4 += __shfl_down(s4, d, 64);
        s5 += __shfl_down(s5, d, 64);
        s6 += __shfl_down(s6, d, 64);
        s7 += __shfl_down(s7, d, 64);
    }

    if (g == 0) {
        size_t o = (size_t)node * DIM + (size_t)sub * 8;
        float4* ap = (float4*)(acc + o);
        float4 x0 = ap[0];
        float4 x1 = ap[1];
        if (!last) {
            __half2 q0 = __floats2half2_rn(s0, s1);
            __half2 q1 = __floats2half2_rn(s2, s3);
            __half2 q2 = __floats2half2_rn(s4, s5);
            __half2 q3 = __floats2half2_rn(s6, s7);
            uint4 w4;
            w4.x = *(const unsigned int*)&q0;
            w4.y = *(const unsigned int*)&q1;
            w4.z = *(const unsigned int*)&q2;
            w4.w = *(const unsigned int*)&q3;
            *(uint4*)(h_out + o) = w4;
            x0.x += s0; x0.y += s1; x0.z += s2; x0.w += s3;
            x1.x += s4; x1.y += s5; x1.z += s6; x1.w += s7;
        } else {
            x0.x = (x0.x + s0) * 0.25f; x0.y = (x0.y + s1) * 0.25f;
            x0.z = (x0.z + s2) * 0.25f; x0.w = (x0.w + s3) * 0.25f;
            x1.x = (x1.x + s4) * 0.25f; x1.y = (x1.y + s5) * 0.25f;
            x1.z = (x1.z + s6) * 0.25f; x1.w = (x1.w + s7) * 0.25f;
        }
        ap[0] = x0;
        ap[1] = x1;
    }
}

extern "C" void kernel_launch(void* const* d_in, const int* in_sizes, int n_in,
                              void* d_out, int out_size, void* d_ws, size_t ws_size,
                              hipStream_t stream) {
    const float* user_emb = (const float*)d_in[0];
    const float* item_emb = (const float*)d_in[1];
    const int*   edge_src = (const int*)d_in[2];
    const int*   edge_dst = (const int*)d_in[3];
    const float* edge_val = (const float*)d_in[4];
    float* out = (float*)d_out;                       // acc lives here

    // ---- workspace layout (bucket_mem unioned with h_b: disjoint lifetimes) ----
    char* p = (char*)d_ws;
    __half* h_a = (__half*)p;                  p += (size_t)N_NODES * DIM * 2;      // 19.2 MB
    unsigned int* csr = (unsigned int*)p;      p += (size_t)N_EDGES * 4;            // 24 MB
    int* row_ptr = (int*)p;                    p += (size_t)(N_NODES + 1 + 3) * 4;
    int* bucket_base = (int*)p;                p += (size_t)(N_BKT + 1 + 1) * 4;
    int* cursors = (int*)p;                    p += (size_t)(N_BKT * N_GRP) * 4;
    int* oflow_cnt = (int*)p;                  p += 16;
    uint2* oflow = (uint2*)p;                  p += (size_t)OFLOW_CAP * 8;
    // union region: bucket_mem (build phase) / h_b (pull phase)
    uint2*  bucket_mem = (uint2*)p;                                                  // 67.2 MB
    __half* h_b        = (__half*)p;                                                 // 19.2 MB

    const int n4 = N_NODES * DIM / 4;
    const int ew_blocks   = (n4 + 255) / 256;
    const int edge_blocks = (N_EDGES + 255) / 256;
    const int pull_blocks = (N_NODES + 3) / 4;

    // ---- build CSR ----
    init_kernel<<<ew_blocks, 256, 0, stream>>>((const float4*)user_emb,
                                               (const float4*)item_emb,
                                               (ushort4*)h_a, (float4*)out, cursors);
    partition_kernel<<<edge_blocks, 256, 0, stream>>>(edge_src, edge_dst, edge_val,
                                                      cursors, oflow_cnt,
                                                      bucket_mem, oflow);
    bucket_scan_kernel<<<1, 1024, 0, stream>>>(cursors, bucket_base, row_ptr);
    bucket_sort_kernel<<<N_BKT, 256, 0, stream>>>(cursors, oflow_cnt, bucket_mem,
                                                  oflow, bucket_base, row_ptr, csr);

    // ---- 3 pull layers, epilogues fused ----
    spmm_pull<<<pull_blocks, 256, 0, stream>>>(row_ptr, csr, h_a, h_b, out, 0);
    spmm_pull<<<pull_blocks, 256, 0, stream>>>(row_ptr, csr, h_b, h_a, out, 0);
    spmm_pull<<<pull_blocks, 256, 0, stream>>>(row_ptr, csr, h_a, h_b, out, 1);
}